// Round 15
// baseline (7411.460 us; speedup 1.0000x reference)
//
#include <hip/hip_runtime.h>
#include <hip/hip_cooperative_groups.h>
#include <stdint.h>

namespace cg = cooperative_groups;

// Echo-state network (fp32 in, fp32 out). Round 15: single cooperative kernel.
// R14 (1791 us): ~24.9 us/step vs ~11 us floor; gap = 70x per-launch overhead
// (dispatch + 768-WG ramp + drain). Fix: ONE hipLaunchCooperativeKernel doing
// all 70 steps with grid.sync() between them; W_res stays L2-hot; waves never
// drain. Step body is byte-identical R14 math (shared __device__ function).
// Fallback: per-step launches (proven R14 path) if cooperative launch errors.

typedef _Float16 f16;
typedef _Float16 f16x8 __attribute__((ext_vector_type(8)));
typedef float floatx4 __attribute__((ext_vector_type(4)));

#define N_TOT 256
#define T_TOT 70
#define V_TOT 64
#define B_TOT 6
#define H_TOT 1024
#define C_TOT 4
#define F_TOT (B_TOT * H_TOT)
#define G_TOT 192
#define LDA 72
#define LO_SCALE 4096.0f
#define LO_INV   (1.0f / 4096.0f)

union H8 { f16 h[8]; uint4 v; };

__global__ __launch_bounds__(256)
void split_f32(const float* __restrict__ src, f16* __restrict__ hi,
               f16* __restrict__ lo, int n)
{
    const int i = (blockIdx.x * 256 + threadIdx.x) * 8;
    if (i + 8 > n) return;
    const float4 a = *(const float4*)&src[i];
    const float4 b = *(const float4*)&src[i + 4];
    const float x[8] = {a.x, a.y, a.z, a.w, b.x, b.y, b.z, b.w};
    H8 H, L;
#pragma unroll
    for (int j = 0; j < 8; ++j) {
        const f16 h = (f16)x[j];
        H.h[j] = h;
        L.h[j] = (f16)((x[j] - (float)h) * LO_SCALE);
    }
    *(uint4*)&hi[i] = H.v;
    *(uint4*)&lo[i] = L.v;
}

__global__ __launch_bounds__(256)
void head_reduce(const float* __restrict__ part,
                 const float* __restrict__ b_lin,
                 float* __restrict__ logits,
                 float* __restrict__ preds)
{
    const int t = blockIdx.x;
    const int n = threadIdx.x;

    float a0 = b_lin[t * C_TOT + 0];
    float a1 = b_lin[t * C_TOT + 1];
    float a2 = b_lin[t * C_TOT + 2];
    float a3 = b_lin[t * C_TOT + 3];

    const float* p = part + (((size_t)t * G_TOT) * N_TOT + n) * C_TOT;
    for (int g = 0; g < G_TOT; ++g) {
        const float4 v = *(const float4*)&p[(size_t)g * N_TOT * C_TOT];
        a0 += v.x; a1 += v.y; a2 += v.z; a3 += v.w;
    }

    float4 o = {a0, a1, a2, a3};
    *(float4*)&logits[((size_t)t * N_TOT + n) * C_TOT] = o;

    int arg = 0;
    float best = a0;
    if (a1 > best) { best = a1; arg = 1; }
    if (a2 > best) { best = a2; arg = 2; }
    if (a3 > best) { best = a3; arg = 3; }
    preds[(size_t)t * N_TOT + n] = (float)arg;
}

// ---------------------------------------------------------------------------
// Shared step body (R14-verified math). Tile 64(M) x 32(I), block id encodes
// (b, mt, it); all operands pre-split (hi, lo*4096) f16; 3 MFMAs/product.
// ---------------------------------------------------------------------------
static __device__ __forceinline__
void step_body(const f16* __restrict__ Xhi,   const f16* __restrict__ Xlo,
               const f16* __restrict__ Whi,   const f16* __restrict__ Wlo,
               const f16* __restrict__ Wihi,  const f16* __restrict__ Wilo,
               const f16* __restrict__ shi_p, const f16* __restrict__ slo_p,
               f16* __restrict__ shi_n,       f16* __restrict__ slo_n,
               const float* __restrict__ W_lin, float* __restrict__ part,
               f16* As_hi, f16* As_lo, f16* Bs_hi, f16* Bs_lo,
               int t, int first)
{
    const int id  = blockIdx.x;
    const int b   = id >> 7;
    const int rem = id & 127;
    const int mt  = rem >> 5;
    const int it  = rem & 31;

    const int tid  = threadIdx.x;
    const int wm   = tid >> 6;
    const int lane = tid & 63;
    const int l16  = lane & 15;
    const int oct  = lane >> 4;

    const int ra = tid >> 2;
    const int ca = (tid & 3) << 4;
    const int rb = tid >> 3;
    const int cb = (tid & 7) << 3;

    floatx4 acc[2], accl[2];
#pragma unroll
    for (int j = 0; j < 2; ++j) { acc[j] = (floatx4)(0.0f); accl[j] = (floatx4)(0.0f); }

    if (!first) {
        const f16* Ah = shi_p + (size_t)(b * N_TOT + mt * 64 + ra) * H_TOT + ca;
        const f16* Al = slo_p + (size_t)(b * N_TOT + mt * 64 + ra) * H_TOT + ca;
        const f16* Bh = Whi   + (size_t)(b * H_TOT + it * 32 + rb) * H_TOT + cb;
        const f16* Bl = Wlo   + (size_t)(b * H_TOT + it * 32 + rb) * H_TOT + cb;

        uint4 pah0, pah1, pal0, pal1, pbh, pbl;
#define LOAD_CHUNK(J0)                                   \
        do {                                             \
            pah0 = *(const uint4*)&Ah[(J0) + 0];         \
            pah1 = *(const uint4*)&Ah[(J0) + 8];         \
            pal0 = *(const uint4*)&Al[(J0) + 0];         \
            pal1 = *(const uint4*)&Al[(J0) + 8];         \
            pbh  = *(const uint4*)&Bh[(J0)];             \
            pbl  = *(const uint4*)&Bl[(J0)];             \
        } while (0)

        LOAD_CHUNK(0);
        for (int kc = 0; kc < 16; ++kc) {
            if (kc) __syncthreads();
            *(uint4*)&As_hi[ra * LDA + ca]     = pah0;
            *(uint4*)&As_hi[ra * LDA + ca + 8] = pah1;
            *(uint4*)&As_lo[ra * LDA + ca]     = pal0;
            *(uint4*)&As_lo[ra * LDA + ca + 8] = pal1;
            *(uint4*)&Bs_hi[rb * LDA + cb]     = pbh;
            *(uint4*)&Bs_lo[rb * LDA + cb]     = pbl;
            __syncthreads();
            if (kc < 15) LOAD_CHUNK((kc + 1) * 64);

#pragma unroll
            for (int kk = 0; kk < 64; kk += 32) {
                const int ar = (wm * 16 + l16) * LDA + kk + oct * 8;
                const f16x8 ah = *(const f16x8*)&As_hi[ar];
                const f16x8 al = *(const f16x8*)&As_lo[ar];
#pragma unroll
                for (int nf = 0; nf < 2; ++nf) {
                    const int br = (nf * 16 + l16) * LDA + kk + oct * 8;
                    const f16x8 bh = *(const f16x8*)&Bs_hi[br];
                    const f16x8 bl = *(const f16x8*)&Bs_lo[br];
                    acc[nf]  = __builtin_amdgcn_mfma_f32_16x16x32_f16(ah, bh, acc[nf], 0, 0, 0);
                    accl[nf] = __builtin_amdgcn_mfma_f32_16x16x32_f16(ah, bl, accl[nf], 0, 0, 0);
                    accl[nf] = __builtin_amdgcn_mfma_f32_16x16x32_f16(al, bh, accl[nf], 0, 0, 0);
                }
            }
        }
#undef LOAD_CHUNK
        __syncthreads();
    }

    // input term: += X_t * W_in[b]^T (K = 64)
    {
        const size_t xb = ((size_t)(mt * 64 + ra) * T_TOT + t) * V_TOT + ca;
        *(uint4*)&As_hi[ra * LDA + ca]     = *(const uint4*)&Xhi[xb];
        *(uint4*)&As_hi[ra * LDA + ca + 8] = *(const uint4*)&Xhi[xb + 8];
        *(uint4*)&As_lo[ra * LDA + ca]     = *(const uint4*)&Xlo[xb];
        *(uint4*)&As_lo[ra * LDA + ca + 8] = *(const uint4*)&Xlo[xb + 8];
        const size_t wb = (size_t)(b * H_TOT + it * 32 + rb) * V_TOT + cb;
        *(uint4*)&Bs_hi[rb * LDA + cb] = *(const uint4*)&Wihi[wb];
        *(uint4*)&Bs_lo[rb * LDA + cb] = *(const uint4*)&Wilo[wb];
        __syncthreads();
#pragma unroll
        for (int kk = 0; kk < 64; kk += 32) {
            const int ar = (wm * 16 + l16) * LDA + kk + oct * 8;
            const f16x8 ah = *(const f16x8*)&As_hi[ar];
            const f16x8 al = *(const f16x8*)&As_lo[ar];
#pragma unroll
            for (int nf = 0; nf < 2; ++nf) {
                const int br = (nf * 16 + l16) * LDA + kk + oct * 8;
                const f16x8 bh = *(const f16x8*)&Bs_hi[br];
                const f16x8 bl = *(const f16x8*)&Bs_lo[br];
                acc[nf]  = __builtin_amdgcn_mfma_f32_16x16x32_f16(ah, bh, acc[nf], 0, 0, 0);
                accl[nf] = __builtin_amdgcn_mfma_f32_16x16x32_f16(ah, bl, accl[nf], 0, 0, 0);
                accl[nf] = __builtin_amdgcn_mfma_f32_16x16x32_f16(al, bh, accl[nf], 0, 0, 0);
            }
        }
    }

    // epilogue: tanh -> split-store state; head partial -> part[]
    const int nbase = mt * 64;
    const int ibase = it * 32;

    const float* wl = W_lin + (size_t)t * C_TOT * F_TOT + b * H_TOT + ibase;
    float w[4][2];
#pragma unroll
    for (int c = 0; c < 4; ++c)
#pragma unroll
        for (int nf = 0; nf < 2; ++nf)
            w[c][nf] = wl[(size_t)c * F_TOT + nf * 16 + l16];

    float sval[2][4];
#pragma unroll
    for (int nf = 0; nf < 2; ++nf)
#pragma unroll
        for (int r = 0; r < 4; ++r) {
            const int m  = wm * 16 + oct * 4 + r;
            const int ii = nf * 16 + l16;
            const float s = tanhf(acc[nf][r] + accl[nf][r] * LO_INV);
            sval[nf][r] = s;
            const f16 h = (f16)s;
            const size_t oidx = (size_t)(b * N_TOT + nbase + m) * H_TOT + ibase + ii;
            shi_n[oidx] = h;
            slo_n[oidx] = (f16)((s - (float)h) * LO_SCALE);
        }

    const int g = b * 32 + it;
#pragma unroll
    for (int r = 0; r < 4; ++r) {
        float v[4];
#pragma unroll
        for (int c = 0; c < 4; ++c) {
            float x = sval[0][r] * w[c][0] + sval[1][r] * w[c][1];
            x += __shfl_xor(x, 1);
            x += __shfl_xor(x, 2);
            x += __shfl_xor(x, 4);
            x += __shfl_xor(x, 8);
            v[c] = x;
        }
        if (l16 == 0) {
            const int n = nbase + wm * 16 + oct * 4 + r;
            float4 o = {v[0], v[1], v[2], v[3]};
            *(float4*)&part[(((size_t)t * G_TOT + g) * N_TOT + n) * C_TOT] = o;
        }
    }
}

// ---------------------------------------------------------------------------
// Cooperative mega-kernel: all 70 timesteps, grid.sync() between steps.
// 768 blocks x 256 threads; __launch_bounds__(256,3) caps VGPR for 3 blk/CU
// co-residency (LDS 27.6 KB -> 3 blk/CU fits 83/160 KB).
// ---------------------------------------------------------------------------
__global__ __launch_bounds__(256, 3)
void esn_all(const f16* __restrict__ Xhi,  const f16* __restrict__ Xlo,
             const f16* __restrict__ Whi,  const f16* __restrict__ Wlo,
             const f16* __restrict__ Wihi, const f16* __restrict__ Wilo,
             f16* __restrict__ sAh, f16* __restrict__ sAl,
             f16* __restrict__ sBh, f16* __restrict__ sBl,
             const float* __restrict__ W_lin, float* __restrict__ part)
{
    __shared__ f16 As_hi[64 * LDA];
    __shared__ f16 As_lo[64 * LDA];
    __shared__ f16 Bs_hi[32 * LDA];
    __shared__ f16 Bs_lo[32 * LDA];

    cg::grid_group grid = cg::this_grid();

    for (int t = 0; t < T_TOT; ++t) {
        const f16 *ph, *pl;
        f16 *nh, *nl;
        if (t & 1) { ph = sBh; pl = sBl; nh = sAh; nl = sAl; }
        else       { ph = sAh; pl = sAl; nh = sBh; nl = sBl; }
        step_body(Xhi, Xlo, Whi, Wlo, Wihi, Wilo, ph, pl, nh, nl,
                  W_lin, part, As_hi, As_lo, Bs_hi, Bs_lo, t, t == 0 ? 1 : 0);
        grid.sync();   // state t visible device-wide before step t+1
    }
}

// Fallback per-step kernel (proven R14 path; same body).
__global__ __launch_bounds__(256)
void esn_step_fused(const f16* __restrict__ Xhi,   const f16* __restrict__ Xlo,
                    const f16* __restrict__ Whi,   const f16* __restrict__ Wlo,
                    const f16* __restrict__ Wihi,  const f16* __restrict__ Wilo,
                    const f16* __restrict__ shi_p, const f16* __restrict__ slo_p,
                    f16* __restrict__ shi_n,       f16* __restrict__ slo_n,
                    const float* __restrict__ W_lin, float* __restrict__ part,
                    int t, int first)
{
    __shared__ f16 As_hi[64 * LDA];
    __shared__ f16 As_lo[64 * LDA];
    __shared__ f16 Bs_hi[32 * LDA];
    __shared__ f16 Bs_lo[32 * LDA];
    step_body(Xhi, Xlo, Whi, Wlo, Wihi, Wilo, shi_p, slo_p, shi_n, slo_n,
              W_lin, part, As_hi, As_lo, Bs_hi, Bs_lo, t, first);
}

extern "C" void kernel_launch(void* const* d_in, const int* in_sizes, int n_in,
                              void* d_out, int out_size, void* d_ws, size_t ws_size,
                              hipStream_t stream) {
    const float* X     = (const float*)d_in[0]; // [256,70,64]
    const float* W_res = (const float*)d_in[1]; // [6,1024,1024]
    const float* W_in  = (const float*)d_in[2]; // [6,1024,64]
    const float* W_lin = (const float*)d_in[3]; // [70,4,6144]
    const float* b_lin = (const float*)d_in[4]; // [70,4]

    float* out    = (float*)d_out;
    float* logits = out;
    float* preds  = out + (size_t)T_TOT * N_TOT * C_TOT;

    const size_t nWres = (size_t)B_TOT * H_TOT * H_TOT;
    const size_t nWin  = (size_t)B_TOT * H_TOT * V_TOT;
    const size_t nX    = (size_t)N_TOT * T_TOT * V_TOT;
    const size_t nS    = (size_t)B_TOT * N_TOT * H_TOT;

    f16* p    = (f16*)d_ws;
    f16* Whi  = p;  p += nWres;
    f16* Wlo  = p;  p += nWres;
    f16* Wihi = p;  p += nWin;
    f16* Wilo = p;  p += nWin;
    f16* Xhi  = p;  p += nX;
    f16* Xlo  = p;  p += nX;
    f16* sAh  = p;  p += nS;
    f16* sAl  = p;  p += nS;
    f16* sBh  = p;  p += nS;
    f16* sBl  = p;  p += nS;
    float* part = (float*)p;   // 55 MB; total ws use ~99 MB (ws ~268 MB)

    split_f32<<<(int)(nWres / 2048), 256, 0, stream>>>(W_res, Whi, Wlo, (int)nWres);
    split_f32<<<(int)(nWin  / 2048), 256, 0, stream>>>(W_in, Wihi, Wilo, (int)nWin);
    split_f32<<<(int)(nX    / 2048), 256, 0, stream>>>(X, Xhi, Xlo, (int)nX);

    void* args[] = {&Xhi, &Xlo, &Whi, &Wlo, &Wihi, &Wilo,
                    &sAh, &sAl, &sBh, &sBl, (void*)&W_lin, &part};
    hipError_t err = hipLaunchCooperativeKernel(
        (const void*)esn_all, dim3(B_TOT * 4 * 32), dim3(256), args, 0, stream);

    if (err != hipSuccess) {
        // fallback: proven per-step path (R14, 1791 us)
        for (int t = 0; t < T_TOT; ++t) {
            const f16 *ph, *pl;
            f16 *nh, *nl;
            if (t & 1) { ph = sBh; pl = sBl; nh = sAh; nl = sAl; }
            else       { ph = sAh; pl = sAl; nh = sBh; nl = sBl; }
            esn_step_fused<<<B_TOT * 4 * 32, 256, 0, stream>>>(
                Xhi, Xlo, Whi, Wlo, Wihi, Wilo, ph, pl, nh, nl,
                W_lin, part, t, t == 0 ? 1 : 0);
        }
    }
    head_reduce<<<T_TOT, 256, 0, stream>>>(part, b_lin, logits, preds);
}

// Round 16
// 2983.115 us; speedup vs baseline: 2.4845x; 2.4845x over previous
//
#include <hip/hip_runtime.h>
#include <stdint.h>

// Echo-state network (fp32 in, fp32 out). Round 16: K-split waves to cut LDS
// read traffic. R15 post-mortem: cooperative grid.sync() = ~85 us/step -> dead
// end; reverted to R14 per-step launches (1791 us). R14 model: step is
// LDS-throughput-bound (~3.5 MB/CU/step; 2/3 of reads are 4 waves redundantly
// reading identical B fragments). Fix: each wave computes the FULL 64x32 tile
// over 4 of 16 K-chunks (kc%4==wave) -> LDS reads halved per wave; partials
// reduced 4-way via LDS scratch (unioned with staging buffers) in the epilogue.
// Numerics identical (hi + lo*4096 f16, 3 MFMAs/product; deterministic fp32
// reorder only). d_ws layout unchanged from R14.

typedef _Float16 f16;
typedef _Float16 f16x8 __attribute__((ext_vector_type(8)));
typedef float floatx4 __attribute__((ext_vector_type(4)));

#define N_TOT 256
#define T_TOT 70
#define V_TOT 64
#define B_TOT 6
#define H_TOT 1024
#define C_TOT 4
#define F_TOT (B_TOT * H_TOT)
#define G_TOT 192
#define LDA 72
#define LO_SCALE 4096.0f
#define LO_INV   (1.0f / 4096.0f)

union H8 { f16 h[8]; uint4 v; };

__global__ __launch_bounds__(256)
void split_f32(const float* __restrict__ src, f16* __restrict__ hi,
               f16* __restrict__ lo, int n)
{
    const int i = (blockIdx.x * 256 + threadIdx.x) * 8;
    if (i + 8 > n) return;
    const float4 a = *(const float4*)&src[i];
    const float4 b = *(const float4*)&src[i + 4];
    const float x[8] = {a.x, a.y, a.z, a.w, b.x, b.y, b.z, b.w};
    H8 H, L;
#pragma unroll
    for (int j = 0; j < 8; ++j) {
        const f16 h = (f16)x[j];
        H.h[j] = h;
        L.h[j] = (f16)((x[j] - (float)h) * LO_SCALE);
    }
    *(uint4*)&hi[i] = H.v;
    *(uint4*)&lo[i] = L.v;
}

__global__ __launch_bounds__(256)
void head_reduce(const float* __restrict__ part,
                 const float* __restrict__ b_lin,
                 float* __restrict__ logits,
                 float* __restrict__ preds)
{
    const int t = blockIdx.x;
    const int n = threadIdx.x;

    float a0 = b_lin[t * C_TOT + 0];
    float a1 = b_lin[t * C_TOT + 1];
    float a2 = b_lin[t * C_TOT + 2];
    float a3 = b_lin[t * C_TOT + 3];

    const float* p = part + (((size_t)t * G_TOT) * N_TOT + n) * C_TOT;
    for (int g = 0; g < G_TOT; ++g) {
        const float4 v = *(const float4*)&p[(size_t)g * N_TOT * C_TOT];
        a0 += v.x; a1 += v.y; a2 += v.z; a3 += v.w;
    }

    float4 o = {a0, a1, a2, a3};
    *(float4*)&logits[((size_t)t * N_TOT + n) * C_TOT] = o;

    int arg = 0;
    float best = a0;
    if (a1 > best) { best = a1; arg = 1; }
    if (a2 > best) { best = a2; arg = 2; }
    if (a3 > best) { best = a3; arg = 3; }
    preds[(size_t)t * N_TOT + n] = (float)arg;
}

// shared-memory arena: staging buffers overlap the epilogue reduce scratch
union SBuf {
    struct {
        f16 As_hi[64 * LDA];
        f16 As_lo[64 * LDA];
        f16 Bs_hi[32 * LDA];
        f16 Bs_lo[32 * LDA];
    } s;                              // 27,648 B
    float red[12][2][64][4];          // 24,576 B (12 src->dst slots x nf x lane)
};

// ---------------------------------------------------------------------------
// Step: tile 64(M) x 32(I), grid = 6*4*32 = 768. Wave w computes the FULL
// 64x32 tile over chunks kc%4==w (4 of 16), accumulating acc[4][2]/accl[4][2];
// epilogue 4-way cross-wave reduce via LDS, then tanh + state + head partial.
// ---------------------------------------------------------------------------
__global__ __launch_bounds__(256, 3)
void esn_step_fused(const f16* __restrict__ Xhi,   const f16* __restrict__ Xlo,
                    const f16* __restrict__ Whi,   const f16* __restrict__ Wlo,
                    const f16* __restrict__ Wihi,  const f16* __restrict__ Wilo,
                    const f16* __restrict__ shi_p, const f16* __restrict__ slo_p,
                    f16* __restrict__ shi_n,       f16* __restrict__ slo_n,
                    const float* __restrict__ W_lin, float* __restrict__ part,
                    int t, int first)
{
    __shared__ SBuf sb;
    f16* As_hi = sb.s.As_hi;
    f16* As_lo = sb.s.As_lo;
    f16* Bs_hi = sb.s.Bs_hi;
    f16* Bs_lo = sb.s.Bs_lo;

    const int id  = blockIdx.x;
    const int b   = id >> 7;
    const int rem = id & 127;
    const int mt  = rem >> 5;
    const int it  = rem & 31;

    const int tid  = threadIdx.x;
    const int wv   = tid >> 6;        // wave 0..3 = K-chunk owner class
    const int lane = tid & 63;
    const int l16  = lane & 15;
    const int oct  = lane >> 4;

    const int ra = tid >> 2;          // A staging row 0..63
    const int ca = (tid & 3) << 4;
    const int rb = tid >> 3;          // B staging row 0..31
    const int cb = (tid & 7) << 3;

    floatx4 acc[4][2], accl[4][2];
#pragma unroll
    for (int m = 0; m < 4; ++m)
#pragma unroll
        for (int j = 0; j < 2; ++j) { acc[m][j] = (floatx4)(0.0f); accl[m][j] = (floatx4)(0.0f); }

    if (!first) {
        const f16* Ah = shi_p + (size_t)(b * N_TOT + mt * 64 + ra) * H_TOT + ca;
        const f16* Al = slo_p + (size_t)(b * N_TOT + mt * 64 + ra) * H_TOT + ca;
        const f16* Bh = Whi   + (size_t)(b * H_TOT + it * 32 + rb) * H_TOT + cb;
        const f16* Bl = Wlo   + (size_t)(b * H_TOT + it * 32 + rb) * H_TOT + cb;

        uint4 pah0, pah1, pal0, pal1, pbh, pbl;
#define LOAD_CHUNK(J0)                                   \
        do {                                             \
            pah0 = *(const uint4*)&Ah[(J0) + 0];         \
            pah1 = *(const uint4*)&Ah[(J0) + 8];         \
            pal0 = *(const uint4*)&Al[(J0) + 0];         \
            pal1 = *(const uint4*)&Al[(J0) + 8];         \
            pbh  = *(const uint4*)&Bh[(J0)];             \
            pbl  = *(const uint4*)&Bl[(J0)];             \
        } while (0)

        LOAD_CHUNK(0);
        for (int kc = 0; kc < 16; ++kc) {
            if (kc) __syncthreads();
            *(uint4*)&As_hi[ra * LDA + ca]     = pah0;
            *(uint4*)&As_hi[ra * LDA + ca + 8] = pah1;
            *(uint4*)&As_lo[ra * LDA + ca]     = pal0;
            *(uint4*)&As_lo[ra * LDA + ca + 8] = pal1;
            *(uint4*)&Bs_hi[rb * LDA + cb]     = pbh;
            *(uint4*)&Bs_lo[rb * LDA + cb]     = pbl;
            __syncthreads();
            if (kc < 15) LOAD_CHUNK((kc + 1) * 64);

            if ((kc & 3) == wv) {                 // this wave owns the chunk
#pragma unroll
                for (int kk = 0; kk < 64; kk += 32) {
                    f16x8 ah[4], al[4];
#pragma unroll
                    for (int m = 0; m < 4; ++m) {
                        const int ar = (m * 16 + l16) * LDA + kk + oct * 8;
                        ah[m] = *(const f16x8*)&As_hi[ar];
                        al[m] = *(const f16x8*)&As_lo[ar];
                    }
#pragma unroll
                    for (int nf = 0; nf < 2; ++nf) {
                        const int br = (nf * 16 + l16) * LDA + kk + oct * 8;
                        const f16x8 bh = *(const f16x8*)&Bs_hi[br];
                        const f16x8 bl = *(const f16x8*)&Bs_lo[br];
#pragma unroll
                        for (int m = 0; m < 4; ++m) {
                            acc[m][nf]  = __builtin_amdgcn_mfma_f32_16x16x32_f16(ah[m], bh, acc[m][nf], 0, 0, 0);
                            accl[m][nf] = __builtin_amdgcn_mfma_f32_16x16x32_f16(ah[m], bl, accl[m][nf], 0, 0, 0);
                            accl[m][nf] = __builtin_amdgcn_mfma_f32_16x16x32_f16(al[m], bh, accl[m][nf], 0, 0, 0);
                        }
                    }
                }
            }
        }
#undef LOAD_CHUNK
        __syncthreads();
    }

    // ---- input term: += X_t * W_in[b]^T (K = 64); waves 0,1 own kk halves ----
    {
        const size_t xb = ((size_t)(mt * 64 + ra) * T_TOT + t) * V_TOT + ca;
        *(uint4*)&As_hi[ra * LDA + ca]     = *(const uint4*)&Xhi[xb];
        *(uint4*)&As_hi[ra * LDA + ca + 8] = *(const uint4*)&Xhi[xb + 8];
        *(uint4*)&As_lo[ra * LDA + ca]     = *(const uint4*)&Xlo[xb];
        *(uint4*)&As_lo[ra * LDA + ca + 8] = *(const uint4*)&Xlo[xb + 8];
        const size_t wb = (size_t)(b * H_TOT + it * 32 + rb) * V_TOT + cb;
        *(uint4*)&Bs_hi[rb * LDA + cb] = *(const uint4*)&Wihi[wb];
        *(uint4*)&Bs_lo[rb * LDA + cb] = *(const uint4*)&Wilo[wb];
        __syncthreads();

        if (wv < 2) {
            const int kk = wv * 32;
            f16x8 ah[4], al[4];
#pragma unroll
            for (int m = 0; m < 4; ++m) {
                const int ar = (m * 16 + l16) * LDA + kk + oct * 8;
                ah[m] = *(const f16x8*)&As_hi[ar];
                al[m] = *(const f16x8*)&As_lo[ar];
            }
#pragma unroll
            for (int nf = 0; nf < 2; ++nf) {
                const int br = (nf * 16 + l16) * LDA + kk + oct * 8;
                const f16x8 bh = *(const f16x8*)&Bs_hi[br];
                const f16x8 bl = *(const f16x8*)&Bs_lo[br];
#pragma unroll
                for (int m = 0; m < 4; ++m) {
                    acc[m][nf]  = __builtin_amdgcn_mfma_f32_16x16x32_f16(ah[m], bh, acc[m][nf], 0, 0, 0);
                    accl[m][nf] = __builtin_amdgcn_mfma_f32_16x16x32_f16(ah[m], bl, accl[m][nf], 0, 0, 0);
                    accl[m][nf] = __builtin_amdgcn_mfma_f32_16x16x32_f16(al[m], bh, accl[m][nf], 0, 0, 0);
                }
            }
        }
        __syncthreads();   // LDS reads done before reduce scratch overwrites
    }

    // ---- 4-way cross-wave reduce: wave wv owns output slab mf==wv ----
    // writer (w -> d, d != w): slot = w*3 + (d < w ? d : d-1)
#pragma unroll
    for (int d = 0; d < 4; ++d) {
        if (d == wv) continue;
        const int slot = wv * 3 + (d < wv ? d : d - 1);
#pragma unroll
        for (int nf = 0; nf < 2; ++nf) {
            floatx4 c = acc[d][nf] + accl[d][nf] * LO_INV;
            *(floatx4*)&sb.red[slot][nf][lane][0] = c;
        }
    }
    __syncthreads();

    floatx4 tot[2];
#pragma unroll
    for (int nf = 0; nf < 2; ++nf)
        tot[nf] = acc[wv][nf] + accl[wv][nf] * LO_INV;
#pragma unroll
    for (int w = 0; w < 4; ++w) {
        if (w == wv) continue;
        const int slot = w * 3 + (wv < w ? wv : wv - 1);
#pragma unroll
        for (int nf = 0; nf < 2; ++nf)
            tot[nf] += *(const floatx4*)&sb.red[slot][nf][lane][0];
    }

    // ---- epilogue: tanh -> split-store state; head partial -> part[] ----
    const int nbase = mt * 64;
    const int ibase = it * 32;

    const float* wl = W_lin + (size_t)t * C_TOT * F_TOT + b * H_TOT + ibase;
    float w[4][2];
#pragma unroll
    for (int c = 0; c < 4; ++c)
#pragma unroll
        for (int nf = 0; nf < 2; ++nf)
            w[c][nf] = wl[(size_t)c * F_TOT + nf * 16 + l16];

    float sval[2][4];
#pragma unroll
    for (int nf = 0; nf < 2; ++nf)
#pragma unroll
        for (int r = 0; r < 4; ++r) {
            const int m  = wv * 16 + oct * 4 + r;
            const int ii = nf * 16 + l16;
            const float s = tanhf(tot[nf][r]);
            sval[nf][r] = s;
            const f16 h = (f16)s;
            const size_t oidx = (size_t)(b * N_TOT + nbase + m) * H_TOT + ibase + ii;
            shi_n[oidx] = h;
            slo_n[oidx] = (f16)((s - (float)h) * LO_SCALE);
        }

    const int g = b * 32 + it;
#pragma unroll
    for (int r = 0; r < 4; ++r) {
        float v[4];
#pragma unroll
        for (int c = 0; c < 4; ++c) {
            float x = sval[0][r] * w[c][0] + sval[1][r] * w[c][1];
            x += __shfl_xor(x, 1);
            x += __shfl_xor(x, 2);
            x += __shfl_xor(x, 4);
            x += __shfl_xor(x, 8);
            v[c] = x;
        }
        if (l16 == 0) {
            const int n = nbase + wv * 16 + oct * 4 + r;
            float4 o = {v[0], v[1], v[2], v[3]};
            *(float4*)&part[(((size_t)t * G_TOT + g) * N_TOT + n) * C_TOT] = o;
        }
    }
}

extern "C" void kernel_launch(void* const* d_in, const int* in_sizes, int n_in,
                              void* d_out, int out_size, void* d_ws, size_t ws_size,
                              hipStream_t stream) {
    const float* X     = (const float*)d_in[0]; // [256,70,64]
    const float* W_res = (const float*)d_in[1]; // [6,1024,1024]
    const float* W_in  = (const float*)d_in[2]; // [6,1024,64]
    const float* W_lin = (const float*)d_in[3]; // [70,4,6144]
    const float* b_lin = (const float*)d_in[4]; // [70,4]

    float* out    = (float*)d_out;
    float* logits = out;
    float* preds  = out + (size_t)T_TOT * N_TOT * C_TOT;

    const size_t nWres = (size_t)B_TOT * H_TOT * H_TOT;
    const size_t nWin  = (size_t)B_TOT * H_TOT * V_TOT;
    const size_t nX    = (size_t)N_TOT * T_TOT * V_TOT;
    const size_t nS    = (size_t)B_TOT * N_TOT * H_TOT;

    f16* p    = (f16*)d_ws;
    f16* Whi  = p;  p += nWres;
    f16* Wlo  = p;  p += nWres;
    f16* Wihi = p;  p += nWin;
    f16* Wilo = p;  p += nWin;
    f16* Xhi  = p;  p += nX;
    f16* Xlo  = p;  p += nX;
    f16* sAh  = p;  p += nS;
    f16* sAl  = p;  p += nS;
    f16* sBh  = p;  p += nS;
    f16* sBl  = p;  p += nS;
    float* part = (float*)p;   // 55 MB; total ws use ~99 MB

    split_f32<<<(int)(nWres / 2048), 256, 0, stream>>>(W_res, Whi, Wlo, (int)nWres);
    split_f32<<<(int)(nWin  / 2048), 256, 0, stream>>>(W_in, Wihi, Wilo, (int)nWin);
    split_f32<<<(int)(nX    / 2048), 256, 0, stream>>>(X, Xhi, Xlo, (int)nX);

    for (int t = 0; t < T_TOT; ++t) {
        const f16 *ph, *pl;
        f16 *nh, *nl;
        if (t & 1) { ph = sBh; pl = sBl; nh = sAh; nl = sAl; }
        else       { ph = sAh; pl = sAl; nh = sBh; nl = sBl; }
        esn_step_fused<<<B_TOT * 4 * 32, 256, 0, stream>>>(
            Xhi, Xlo, Whi, Wlo, Wihi, Wilo, ph, pl, nh, nl,
            W_lin, part, t, t == 0 ? 1 : 0);
    }
    head_reduce<<<T_TOT, 256, 0, stream>>>(part, b_lin, logits, preds);
}